// Round 2
// baseline (245.426 us; speedup 1.0000x reference)
//
#include <hip/hip_runtime.h>

// TokenImportanceRouter: scores[b,t] = scale * (hidden[b,t,:]·w_eff[b] + c[b])
//   h̄[b] = mean_t hidden[b,t,:]            (B,D)   pass 1 over hidden
//   k̄[b] = Wk·h̄[b] + bk                    (B,Dr)
//   w_eff[b] = Wqᵀ·k̄[b]                    (B,D)
//   c[b]     = bq·k̄[b]
//   scores[b,t] = scale*(hidden[b,t]·w_eff[b] + c[b])   pass 2 over hidden

constexpr int B  = 4;
constexpr int T  = 4096;
constexpr int D  = 2048;
constexpr int DR = 512;

constexpr int NT_CHUNKS = 128;   // T-split for the column-sum pass
constexpr int NR_CHUNKS = 16;    // r-split for the w_eff pass

// ---------------------------------------------------------------- pass 1
// column sum of hidden over t, per batch.  grid (D/1024, B, NT_CHUNKS), block 256.
__global__ __launch_bounds__(256)
void colsum_k(const float* __restrict__ hidden, float* __restrict__ hsum) {
    const int d4 = blockIdx.x * blockDim.x + threadIdx.x;   // float4 column index
    const int b  = blockIdx.y;
    const int rows = T / NT_CHUNKS;                         // 32
    const int t0 = blockIdx.z * rows;
    const float4* src = reinterpret_cast<const float4*>(hidden + (size_t)b * T * D);
    float4 acc = make_float4(0.f, 0.f, 0.f, 0.f);
#pragma unroll 4
    for (int t = t0; t < t0 + rows; ++t) {
        float4 v = src[(size_t)t * (D / 4) + d4];
        acc.x += v.x; acc.y += v.y; acc.z += v.z; acc.w += v.w;
    }
    float* dst = hsum + (size_t)b * D + d4 * 4;
    atomicAdd(dst + 0, acc.x);
    atomicAdd(dst + 1, acc.y);
    atomicAdd(dst + 2, acc.z);
    atomicAdd(dst + 3, acc.w);
}

// ---------------------------------------------------------------- k̄ = Wk·(hsum/T) + bk
// grid (DR/4, B), block 256 = 4 waves, one r-row per wave.
__global__ __launch_bounds__(256)
void kbar_k(const float* __restrict__ Wk, const float* __restrict__ bk,
            const float* __restrict__ hsum, float* __restrict__ kbar) {
    const int b    = blockIdx.y;
    const int wave = threadIdx.x >> 6;
    const int lane = threadIdx.x & 63;
    const int r    = blockIdx.x * 4 + wave;
    const float4* wrow = reinterpret_cast<const float4*>(Wk + (size_t)r * D);
    const float4* h    = reinterpret_cast<const float4*>(hsum + (size_t)b * D);
    float acc = 0.f;
#pragma unroll
    for (int i = 0; i < D / 4 / 64; ++i) {     // 8
        const int idx = i * 64 + lane;
        float4 wv = wrow[idx];
        float4 hv = h[idx];
        acc += wv.x * hv.x + wv.y * hv.y + wv.z * hv.z + wv.w * hv.w;
    }
#pragma unroll
    for (int off = 32; off; off >>= 1) acc += __shfl_down(acc, off);
    if (lane == 0) kbar[b * DR + r] = acc * (1.0f / T) + bk[r];
}

// ---------------------------------------------------------------- w_eff[b,d] = Σ_r Wq[r,d]·k̄[b,r]
// grid (D/256, NR_CHUNKS), block 256.  Wq read exactly once; all 4 batches per pass.
__global__ __launch_bounds__(256)
void wqeff_k(const float* __restrict__ Wq, const float* __restrict__ kbar,
             float* __restrict__ wqeff) {
    const int d     = blockIdx.x * 256 + threadIdx.x;
    const int rrows = DR / NR_CHUNKS;          // 32
    const int r0    = blockIdx.y * rrows;
    float acc[B] = {0.f, 0.f, 0.f, 0.f};
    for (int r = r0; r < r0 + rrows; ++r) {
        const float w = Wq[(size_t)r * D + d];
#pragma unroll
        for (int b = 0; b < B; ++b) acc[b] += w * kbar[b * DR + r];
    }
#pragma unroll
    for (int b = 0; b < B; ++b) atomicAdd(&wqeff[b * D + d], acc[b]);
}

// ---------------------------------------------------------------- c[b] = bq·k̄[b]
__global__ __launch_bounds__(64)
void cterm_k(const float* __restrict__ bq, const float* __restrict__ kbar,
             float* __restrict__ cterm) {
    const int b    = blockIdx.x;
    const int lane = threadIdx.x;              // 64 threads
    float acc = 0.f;
#pragma unroll
    for (int i = 0; i < DR / 64; ++i) {        // 8
        const int idx = i * 64 + lane;
        acc += bq[idx] * kbar[b * DR + idx];
    }
#pragma unroll
    for (int off = 32; off; off >>= 1) acc += __shfl_down(acc, off);
    if (lane == 0) cterm[b] = acc;
}

// ---------------------------------------------------------------- pass 2
// scores[b,t] = scale*(hidden[b,t]·w_eff[b] + c[b]).  grid (T/4, B), block 256,
// one row per wave; w_eff row (8 KiB) stays hot in L1/L2.
__global__ __launch_bounds__(256)
void scores_k(const float* __restrict__ hidden, const float* __restrict__ wqeff,
              const float* __restrict__ cterm, float* __restrict__ out) {
    const int b    = blockIdx.y;
    const int wave = threadIdx.x >> 6;
    const int lane = threadIdx.x & 63;
    const int t    = blockIdx.x * 4 + wave;
    const float4* hrow = reinterpret_cast<const float4*>(hidden + ((size_t)b * T + t) * D);
    const float4* w    = reinterpret_cast<const float4*>(wqeff + (size_t)b * D);
    float acc = 0.f;
#pragma unroll
    for (int i = 0; i < D / 4 / 64; ++i) {     // 8
        const int idx = i * 64 + lane;
        float4 hv = hrow[idx];
        float4 wv = w[idx];
        acc += hv.x * wv.x + hv.y * wv.y + hv.z * wv.z + hv.w * wv.w;
    }
#pragma unroll
    for (int off = 32; off; off >>= 1) acc += __shfl_down(acc, off);
    // scale = DR^-0.5 = 512^-0.5
    if (lane == 0) out[(size_t)b * T + t] = (acc + cterm[b]) * 4.41941738241592e-02f;
}

extern "C" void kernel_launch(void* const* d_in, const int* in_sizes, int n_in,
                              void* d_out, int out_size, void* d_ws, size_t ws_size,
                              hipStream_t stream) {
    const float* hidden = (const float*)d_in[0];
    const float* Wq     = (const float*)d_in[1];
    const float* bq     = (const float*)d_in[2];
    const float* Wk     = (const float*)d_in[3];
    const float* bk     = (const float*)d_in[4];
    float* out = (float*)d_out;

    // workspace layout (floats): [hsum B*D][wqeff B*D][kbar B*DR][cterm B]
    float* hsum  = (float*)d_ws;
    float* wqeff = hsum + B * D;
    float* kbar  = wqeff + B * D;
    float* cterm = kbar + B * DR;

    // zero the atomically-accumulated regions (hsum + wqeff are contiguous)
    hipMemsetAsync(d_ws, 0, (size_t)(2 * B * D) * sizeof(float), stream);

    dim3 g1(D / (4 * 256), B, NT_CHUNKS);          // (2, 4, 128) = 1024 blocks
    colsum_k<<<g1, 256, 0, stream>>>(hidden, hsum);

    dim3 g2(DR / 4, B);                            // (128, 4)
    kbar_k<<<g2, 256, 0, stream>>>(Wk, bk, hsum, kbar);

    dim3 g3(D / 256, NR_CHUNKS);                   // (8, 16)
    wqeff_k<<<g3, 256, 0, stream>>>(Wq, kbar, wqeff);

    cterm_k<<<B, 64, 0, stream>>>(bq, kbar, cterm);

    dim3 g5(T / 4, B);                             // (1024, 4)
    scores_k<<<g5, 256, 0, stream>>>(hidden, wqeff, cterm, out);
}

// Round 3
// 244.110 us; speedup vs baseline: 1.0054x; 1.0054x over previous
//
#include <hip/hip_runtime.h>

// TokenImportanceRouter: scores[b,t] = scale * (hidden[b,t,:]·w_eff[b] + c[b])
//   h̄[b] = mean_t hidden[b,t,:]            (B,D)   pass 1 over hidden (2-stage, no atomics)
//   k̄[b] = Wk·h̄[b] + bk                    (B,Dr)
//   w_eff[b] = Wqᵀ·k̄[b]                    (B,D)   (2-stage partials, no atomics)
//   c[b]     = bq·k̄[b]
//   scores[b,t] = scale*(hidden[b,t]·w_eff[b] + c[b])   pass 2 over hidden

constexpr int B  = 4;
constexpr int T  = 4096;
constexpr int D  = 2048;
constexpr int DR = 512;

constexpr int NZ  = 128;   // T-split for column-sum partials
constexpr int NRC = 4;     // r-chunks for w_eff partials

// ---------------------------------------------------------------- pass 1a
// partial column sums. grid (D/1024, B, NZ), block 256. Disjoint writes.
__global__ __launch_bounds__(256)
void colsum_part_k(const float* __restrict__ hidden, float* __restrict__ part) {
    const int d4 = blockIdx.x * 256 + threadIdx.x;          // float4 column [0,512)
    const int b  = blockIdx.y;
    const int z  = blockIdx.z;
    const int rows = T / NZ;                                // 32
    const int t0 = z * rows;
    const float4* src = reinterpret_cast<const float4*>(hidden + (size_t)b * T * D);
    float4 acc = make_float4(0.f, 0.f, 0.f, 0.f);
#pragma unroll 8
    for (int t = t0; t < t0 + rows; ++t) {
        float4 v = src[(size_t)t * (D / 4) + d4];
        acc.x += v.x; acc.y += v.y; acc.z += v.z; acc.w += v.w;
    }
    float4* dst = reinterpret_cast<float4*>(part + ((size_t)z * B + b) * D);
    dst[d4] = acc;
}

// ---------------------------------------------------------------- pass 1b
// fold NZ partials -> hsum. grid (D/256, B), block 256.
__global__ __launch_bounds__(256)
void hsum_reduce_k(const float* __restrict__ part, float* __restrict__ hsum) {
    const int d = blockIdx.x * 256 + threadIdx.x;
    const int b = blockIdx.y;
    float acc = 0.f;
#pragma unroll 8
    for (int z = 0; z < NZ; ++z) acc += part[((size_t)z * B + b) * D + d];
    hsum[(size_t)b * D + d] = acc;
}

// ---------------------------------------------------------------- k̄ = Wk·(hsum/T) + bk
// grid (DR/4, B), block 256 = 4 waves, one r-row per wave.
__global__ __launch_bounds__(256)
void kbar_k(const float* __restrict__ Wk, const float* __restrict__ bk,
            const float* __restrict__ hsum, float* __restrict__ kbar) {
    const int b    = blockIdx.y;
    const int wave = threadIdx.x >> 6;
    const int lane = threadIdx.x & 63;
    const int r    = blockIdx.x * 4 + wave;
    const float4* wrow = reinterpret_cast<const float4*>(Wk + (size_t)r * D);
    const float4* h    = reinterpret_cast<const float4*>(hsum + (size_t)b * D);
    float acc = 0.f;
#pragma unroll
    for (int i = 0; i < D / 4 / 64; ++i) {     // 8
        const int idx = i * 64 + lane;
        float4 wv = wrow[idx];
        float4 hv = h[idx];
        acc += wv.x * hv.x + wv.y * hv.y + wv.z * hv.z + wv.w * hv.w;
    }
#pragma unroll
    for (int off = 32; off; off >>= 1) acc += __shfl_down(acc, off);
    if (lane == 0) kbar[b * DR + r] = acc * (1.0f / T) + bk[r];
}

// ---------------------------------------------------------------- w_eff partials
// wqpart[c][b][d] = Σ_{r in chunk c} Wq[r,d]·k̄[b,r].  grid (D/256, B, NRC), block 256.
__global__ __launch_bounds__(256)
void wqpart_k(const float* __restrict__ Wq, const float* __restrict__ kbar,
              float* __restrict__ wqpart) {
    const int d  = blockIdx.x * 256 + threadIdx.x;
    const int b  = blockIdx.y;
    const int c  = blockIdx.z;
    const int r0 = c * (DR / NRC);             // 128-row chunk
    const float* kb = kbar + b * DR;
    float acc = 0.f;
#pragma unroll 8
    for (int r = r0; r < r0 + DR / NRC; ++r)
        acc += Wq[(size_t)r * D + d] * kb[r];
    wqpart[((size_t)c * B + b) * D + d] = acc;
}

// ---------------------------------------------------------------- finish: fold wq partials + cterm
// grid (D/256, B), block 256.  block x==0 additionally computes cterm[b]=bq·k̄[b].
__global__ __launch_bounds__(256)
void finish_k(const float* __restrict__ wqpart, const float* __restrict__ bq,
              const float* __restrict__ kbar, float* __restrict__ wqeff,
              float* __restrict__ cterm) {
    __shared__ float wsum[4];
    const int d = blockIdx.x * 256 + threadIdx.x;
    const int b = blockIdx.y;
    float acc = 0.f;
#pragma unroll
    for (int c = 0; c < NRC; ++c) acc += wqpart[((size_t)c * B + b) * D + d];
    wqeff[(size_t)b * D + d] = acc;

    if (blockIdx.x == 0) {
        const float* kb = kbar + b * DR;
        const int tid = threadIdx.x;
        float a2 = bq[tid] * kb[tid] + bq[tid + 256] * kb[tid + 256];
#pragma unroll
        for (int off = 32; off; off >>= 1) a2 += __shfl_down(a2, off);
        if ((tid & 63) == 0) wsum[tid >> 6] = a2;
        __syncthreads();
        if (tid == 0) cterm[b] = wsum[0] + wsum[1] + wsum[2] + wsum[3];
    }
}

// ---------------------------------------------------------------- pass 2
// scores[b,t] = scale*(hidden[b,t]·w_eff[b] + c[b]).  grid (T/4, B), block 256,
// one row per wave; w_eff row (8 KiB) stays hot in L1/L2.
__global__ __launch_bounds__(256)
void scores_k(const float* __restrict__ hidden, const float* __restrict__ wqeff,
              const float* __restrict__ cterm, float* __restrict__ out) {
    const int b    = blockIdx.y;
    const int wave = threadIdx.x >> 6;
    const int lane = threadIdx.x & 63;
    const int t    = blockIdx.x * 4 + wave;
    const float4* hrow = reinterpret_cast<const float4*>(hidden + ((size_t)b * T + t) * D);
    const float4* w    = reinterpret_cast<const float4*>(wqeff + (size_t)b * D);
    float acc = 0.f;
#pragma unroll
    for (int i = 0; i < D / 4 / 64; ++i) {     // 8
        const int idx = i * 64 + lane;
        float4 hv = hrow[idx];
        float4 wv = w[idx];
        acc += hv.x * wv.x + hv.y * wv.y + hv.z * wv.z + hv.w * wv.w;
    }
#pragma unroll
    for (int off = 32; off; off >>= 1) acc += __shfl_down(acc, off);
    // scale = DR^-0.5 = 512^-0.5
    if (lane == 0) out[(size_t)b * T + t] = (acc + cterm[b]) * 4.41941738241592e-02f;
}

extern "C" void kernel_launch(void* const* d_in, const int* in_sizes, int n_in,
                              void* d_out, int out_size, void* d_ws, size_t ws_size,
                              hipStream_t stream) {
    const float* hidden = (const float*)d_in[0];
    const float* Wq     = (const float*)d_in[1];
    const float* bq     = (const float*)d_in[2];
    const float* Wk     = (const float*)d_in[3];
    const float* bk     = (const float*)d_in[4];
    float* out = (float*)d_out;

    // workspace layout (floats), all written before read — no zero-init needed:
    // [part NZ*B*D = 1M][hsum B*D][kbar B*DR][wqpart NRC*B*D][wqeff B*D][cterm B]
    float* part   = (float*)d_ws;
    float* hsum   = part + (size_t)NZ * B * D;
    float* kbar   = hsum + B * D;
    float* wqpart = kbar + B * DR;
    float* wqeff  = wqpart + (size_t)NRC * B * D;
    float* cterm  = wqeff + B * D;

    dim3 g1(D / 1024, B, NZ);                      // (2, 4, 128) = 1024 blocks
    colsum_part_k<<<g1, 256, 0, stream>>>(hidden, part);

    dim3 g1b(D / 256, B);                          // (8, 4)
    hsum_reduce_k<<<g1b, 256, 0, stream>>>(part, hsum);

    dim3 g2(DR / 4, B);                            // (128, 4)
    kbar_k<<<g2, 256, 0, stream>>>(Wk, bk, hsum, kbar);

    dim3 g3(D / 256, B, NRC);                      // (8, 4, 4)
    wqpart_k<<<g3, 256, 0, stream>>>(Wq, kbar, wqpart);

    dim3 g4(D / 256, B);                           // (8, 4)
    finish_k<<<g4, 256, 0, stream>>>(wqpart, bq, kbar, wqeff, cterm);

    dim3 g5(T / 4, B);                             // (1024, 4)
    scores_k<<<g5, 256, 0, stream>>>(hidden, wqeff, cterm, out);
}